// Round 1
// baseline (4144.327 us; speedup 1.0000x reference)
//
#include <hip/hip_runtime.h>
#include <math.h>

#define T 512
#define D 128
#define H 512
#define EMB 256
#define Z4 2048          // 4*H
#define NWG 32           // workgroups in recurrent kernels
#define SLICE 16         // hidden units per wg (H/NWG)
#define NTH 256          // threads per wg

// ---- device-global scratch (rewritten every call; counters reset in k_xp) ----
__device__ float g_xp[T * Z4];            // encoder input projections + bh
__device__ float g_hbuf_e[2][H];          // encoder h double buffer
__device__ float g_hbuf_d[2][H];          // decoder h double buffer
__device__ float g_xpart[2][NWG][D];      // decoder x partial slots
__device__ float g_hd0[H];                // decoder initial hidden
__device__ unsigned g_ctr_e;              // encoder barrier counter
__device__ unsigned g_ctr_d;              // decoder barrier counter

__device__ __forceinline__ float aload(const float* p) {
    return __hip_atomic_load(p, __ATOMIC_RELAXED, __HIP_MEMORY_SCOPE_AGENT);
}
__device__ __forceinline__ void astore(float* p, float v) {
    __hip_atomic_store(p, v, __ATOMIC_RELAXED, __HIP_MEMORY_SCOPE_AGENT);
}
__device__ __forceinline__ float sigm(float x) { return 1.0f / (1.0f + expf(-x)); }

// ---- K1: XP = trajectory @ enc_Wi + enc_bh  (parallel) ----
#define TT 16
__global__ __launch_bounds__(256, 1)
void k_xp(const float* __restrict__ traj, const float* __restrict__ Wi,
          const float* __restrict__ bh) {
    const int tid = threadIdx.x;
    if (blockIdx.x == 0 && blockIdx.y == 0 && tid == 0) {
        g_ctr_e = 0u;   // reset barrier counters each call (kernel-boundary ordered)
        g_ctr_d = 0u;
    }
    const int jc = blockIdx.x;     // 0..7 column chunk
    const int t0 = blockIdx.y * TT;
    const int j  = jc * 256 + tid;

    __shared__ float tl[TT * D];
#pragma unroll
    for (int r = 0; r < (TT * D) / 256; ++r)
        tl[r * 256 + tid] = traj[t0 * D + r * 256 + tid];
    __syncthreads();

    float acc[TT];
#pragma unroll
    for (int tt = 0; tt < TT; ++tt) acc[tt] = 0.f;
    for (int i = 0; i < D; ++i) {
        const float wv = Wi[i * Z4 + j];
#pragma unroll
        for (int tt = 0; tt < TT; ++tt) acc[tt] += tl[tt * D + i] * wv;
    }
    const float bv = bh[j];
#pragma unroll
    for (int tt = 0; tt < TT; ++tt)
        g_xp[(t0 + tt) * Z4 + j] = acc[tt] + bv;
}

// ---- K2: encoder recurrence (32 wgs, weights in VGPRs) ----
__global__ __launch_bounds__(NTH, 1)
void k_enc(const float* __restrict__ Wh) {
    const int w   = blockIdx.x;
    const int tid = threadIdx.x;
    const int jl  = tid & 63;        // local z column 0..63
    const int p   = tid >> 6;        // input part 0..3 (h range [128p,128p+128))
    const int k0  = w * SLICE;
    const int gcol = (jl >> 4) * H + k0 + (jl & 15);   // global z column

    // per-thread weight slice in registers
    float wh[128];
#pragma unroll
    for (int q = 0; q < 128; ++q)
        wh[q] = Wh[(p * 128 + q) * Z4 + gcol];

    __shared__ float h_lds[H];
    __shared__ float zred[NTH];
    __shared__ float zfin[64];

    float creg = 0.f;   // cell state, used by tid < SLICE

    for (int t = 0; t < T; ++t) {
        const float xpv = (p == 0) ? g_xp[t * Z4 + gcol] : 0.f;

        if (t > 0) {
            if (tid == 0) {
                while (__hip_atomic_load(&g_ctr_e, __ATOMIC_ACQUIRE,
                                         __HIP_MEMORY_SCOPE_AGENT) < (unsigned)(NWG * t)) {}
            }
            __syncthreads();
#pragma unroll
            for (int r = 0; r < H / NTH; ++r)
                h_lds[r * NTH + tid] = aload(&g_hbuf_e[t & 1][r * NTH + tid]);
        } else {
#pragma unroll
            for (int r = 0; r < H / NTH; ++r)
                h_lds[r * NTH + tid] = 0.f;
        }
        __syncthreads();

        float acc = xpv;
#pragma unroll
        for (int q4 = 0; q4 < 32; ++q4) {
            const float4 hv = *reinterpret_cast<const float4*>(&h_lds[p * 128 + q4 * 4]);
            acc += hv.x * wh[q4 * 4 + 0] + hv.y * wh[q4 * 4 + 1] +
                   hv.z * wh[q4 * 4 + 2] + hv.w * wh[q4 * 4 + 3];
        }
        zred[tid] = acc;
        __syncthreads();
        if (tid < 64)
            zfin[tid] = zred[tid] + zred[64 + tid] + zred[128 + tid] + zred[192 + tid];
        __syncthreads();
        if (tid < SLICE) {
            const float zi = zfin[tid], zf = zfin[16 + tid],
                        zg = zfin[32 + tid], zo = zfin[48 + tid];
            const float cn = sigm(zf) * creg + sigm(zi) * tanhf(zg);
            creg = cn;
            const float hn = sigm(zo) * tanhf(cn);
            astore(&g_hbuf_e[(t + 1) & 1][k0 + tid], hn);
        }
        __syncthreads();   // drain publishes (per-wave vmcnt) before flag
        if (tid == 0)
            __hip_atomic_fetch_add(&g_ctr_e, 1u, __ATOMIC_RELEASE,
                                   __HIP_MEMORY_SCOPE_AGENT);
    }
}

// ---- K3: embedding + decoder init (1 wg) ----
__global__ __launch_bounds__(256, 1)
void k_emb(const float* __restrict__ embW, const float* __restrict__ embB,
           const float* __restrict__ diW, const float* __restrict__ diB,
           float* __restrict__ out) {
    const int tid = threadIdx.x;
    __shared__ float h_l[H];
    __shared__ float e_l[EMB];
#pragma unroll
    for (int r = 0; r < H / 256; ++r)
        h_l[r * 256 + tid] = aload(&g_hbuf_e[T & 1][r * 256 + tid]);  // T&1 == 0
    __syncthreads();

    float acc = embB[tid];
    for (int i = 0; i < H; ++i)
        acc += h_l[i] * embW[i * EMB + tid];
    e_l[tid] = acc;
    out[T * D + tid] = acc;            // embedding output
    __syncthreads();

#pragma unroll
    for (int r = 0; r < H / 256; ++r) {
        const int k = r * 256 + tid;
        float a2 = diB[k];
        for (int e = 0; e < EMB; ++e)
            a2 += e_l[e] * diW[e * H + k];
        g_hd0[k] = a2;
    }
}

// ---- K4: decoder recurrence + per-step output (32 wgs) ----
__global__ __launch_bounds__(NTH, 1)
void k_dec(const float* __restrict__ Wi, const float* __restrict__ Wh,
           const float* __restrict__ bh, const float* __restrict__ Wt,
           const float* __restrict__ bt, float* __restrict__ out) {
    const int w   = blockIdx.x;
    const int tid = threadIdx.x;
    const int jl  = tid & 63;
    const int p   = tid >> 6;        // part: x range [32p,32p+32), h range [128p,128p+128)
    const int k0  = w * SLICE;
    const int gcol = (jl >> 4) * H + k0 + (jl & 15);

    float wx[32], wh[128];
#pragma unroll
    for (int q = 0; q < 32; ++q)
        wx[q] = Wi[(p * 32 + q) * Z4 + gcol];
#pragma unroll
    for (int q = 0; q < 128; ++q)
        wh[q] = Wh[(p * 128 + q) * Z4 + gcol];
    const float bhz = (tid < 64) ? bh[(tid >> 4) * H + k0 + (tid & 15)] : 0.f;

    __shared__ float h_lds[H];
    __shared__ float xs_lds[D];
    __shared__ float zred[NTH];
    __shared__ float zfin[64];
    __shared__ float hs_lds[SLICE];

    float creg = 0.f;

    for (int s = 0; s < T; ++s) {
        // prefetch this step's output-weight rows (independent of h -> hides HBM latency)
        float wpre[SLICE];
        float btv = 0.f;
        if (tid < D) {
#pragma unroll
            for (int kk = 0; kk < SLICE; ++kk)
                wpre[kk] = Wt[((size_t)s * H + k0 + kk) * D + tid];
            if (w == 0) btv = bt[s * D + tid];
        }

        if (s > 0) {
            if (tid == 0) {
                while (__hip_atomic_load(&g_ctr_d, __ATOMIC_ACQUIRE,
                                         __HIP_MEMORY_SCOPE_AGENT) < (unsigned)(NWG * s)) {}
            }
            __syncthreads();
#pragma unroll
            for (int r = 0; r < H / NTH; ++r)
                h_lds[r * NTH + tid] = aload(&g_hbuf_d[s & 1][r * NTH + tid]);
            {   // sum x partial slots: 256 threads = (d 0..127) x (half 0..1)
                const int d  = tid & (D - 1);
                const int hf = tid >> 7;
                float sx = 0.f;
#pragma unroll
                for (int q = 0; q < NWG / 2; ++q)
                    sx += aload(&g_xpart[s & 1][hf * (NWG / 2) + q][d]);
                zred[tid] = sx;
            }
            __syncthreads();
            if (tid < D) xs_lds[tid] = zred[tid] + zred[D + tid];
            __syncthreads();
            if (w == 0 && tid < D) out[(size_t)(s - 1) * D + tid] = xs_lds[tid];
        } else {
#pragma unroll
            for (int r = 0; r < H / NTH; ++r)
                h_lds[r * NTH + tid] = g_hd0[r * NTH + tid];
            if (tid < D) xs_lds[tid] = 0.f;
            __syncthreads();
        }

        float acc = 0.f;
#pragma unroll
        for (int q4 = 0; q4 < 8; ++q4) {
            const float4 xv = *reinterpret_cast<const float4*>(&xs_lds[p * 32 + q4 * 4]);
            acc += xv.x * wx[q4 * 4 + 0] + xv.y * wx[q4 * 4 + 1] +
                   xv.z * wx[q4 * 4 + 2] + xv.w * wx[q4 * 4 + 3];
        }
#pragma unroll
        for (int q4 = 0; q4 < 32; ++q4) {
            const float4 hv = *reinterpret_cast<const float4*>(&h_lds[p * 128 + q4 * 4]);
            acc += hv.x * wh[q4 * 4 + 0] + hv.y * wh[q4 * 4 + 1] +
                   hv.z * wh[q4 * 4 + 2] + hv.w * wh[q4 * 4 + 3];
        }
        zred[tid] = acc;
        __syncthreads();
        if (tid < 64)
            zfin[tid] = zred[tid] + zred[64 + tid] + zred[128 + tid] + zred[192 + tid] + bhz;
        __syncthreads();
        if (tid < SLICE) {
            const float zi = zfin[tid], zf = zfin[16 + tid],
                        zg = zfin[32 + tid], zo = zfin[48 + tid];
            const float cn = sigm(zf) * creg + sigm(zi) * tanhf(zg);
            creg = cn;
            const float hn = sigm(zo) * tanhf(cn);
            hs_lds[tid] = hn;
            astore(&g_hbuf_d[(s + 1) & 1][k0 + tid], hn);
        }
        __syncthreads();
        if (tid < D) {
            float px = btv;
#pragma unroll
            for (int kk = 0; kk < SLICE; ++kk)
                px += hs_lds[kk] * wpre[kk];
            astore(&g_xpart[(s + 1) & 1][w][tid], px);
        }
        __syncthreads();
        if (tid == 0)
            __hip_atomic_fetch_add(&g_ctr_d, 1u, __ATOMIC_RELEASE,
                                   __HIP_MEMORY_SCOPE_AGENT);
    }

    // final reconstruction row (x_512), summed by wg 0
    if (w == 0) {
        if (tid == 0) {
            while (__hip_atomic_load(&g_ctr_d, __ATOMIC_ACQUIRE,
                                     __HIP_MEMORY_SCOPE_AGENT) < (unsigned)(NWG * T)) {}
        }
        __syncthreads();
        {
            const int d  = tid & (D - 1);
            const int hf = tid >> 7;
            float sx = 0.f;
#pragma unroll
            for (int q = 0; q < NWG / 2; ++q)
                sx += aload(&g_xpart[T & 1][hf * (NWG / 2) + q][d]);
            zred[tid] = sx;
        }
        __syncthreads();
        if (tid < D) out[(size_t)(T - 1) * D + tid] = zred[tid] + zred[D + tid];
    }
}

extern "C" void kernel_launch(void* const* d_in, const int* in_sizes, int n_in,
                              void* d_out, int out_size, void* d_ws, size_t ws_size,
                              hipStream_t stream) {
    const float* traj  = (const float*)d_in[0];
    const float* encWi = (const float*)d_in[1];
    const float* encWh = (const float*)d_in[2];
    const float* encbh = (const float*)d_in[3];
    const float* embW  = (const float*)d_in[4];
    const float* embB  = (const float*)d_in[5];
    const float* diW   = (const float*)d_in[6];
    const float* diB   = (const float*)d_in[7];
    const float* decWi = (const float*)d_in[8];
    const float* decWh = (const float*)d_in[9];
    const float* decbh = (const float*)d_in[10];
    const float* doW   = (const float*)d_in[11];
    const float* dob   = (const float*)d_in[12];
    float* out = (float*)d_out;

    k_xp<<<dim3(8, T / TT), dim3(256), 0, stream>>>(traj, encWi, encbh);
    k_enc<<<dim3(NWG), dim3(NTH), 0, stream>>>(encWh);
    k_emb<<<dim3(1), dim3(256), 0, stream>>>(embW, embB, diW, diB, out);
    k_dec<<<dim3(NWG), dim3(NTH), 0, stream>>>(decWi, decWh, decbh, doW, dob, out);
}

// Round 2
// 2818.203 us; speedup vs baseline: 1.4706x; 1.4706x over previous
//
#include <hip/hip_runtime.h>
#include <math.h>

#define T 512
#define D 128
#define H 512
#define EMB 256
#define Z4 2048          // 4*H
#define NWG 16           // workgroups in recurrent kernels
#define SLICE 32         // hidden units per wg (H/NWG)
#define NTH 512          // threads per wg

typedef unsigned long long u64;
typedef unsigned int u32;

// ---- device-global scratch (tags zeroed by k_xp each call) ----
__device__ float g_xp[T * Z4];        // encoder input projections + bh
__device__ u64 g_he[2][H];            // encoder h, packed {tag,val}, slot = tag&1
__device__ u64 g_hd[2][H];            // decoder h, packed
__device__ u64 g_xq[2][NWG][D];       // decoder x partials, packed
__device__ float g_hd0[H];            // decoder initial hidden

__device__ __forceinline__ u64 aload64(const u64* p) {
    return __hip_atomic_load(p, __ATOMIC_RELAXED, __HIP_MEMORY_SCOPE_AGENT);
}
__device__ __forceinline__ void astore64(u64* p, u64 v) {
    __hip_atomic_store(p, v, __ATOMIC_RELAXED, __HIP_MEMORY_SCOPE_AGENT);
}
__device__ __forceinline__ u64 pack2(u32 tag, float v) {
    return ((u64)tag << 32) | (u64)__float_as_uint(v);
}
__device__ __forceinline__ float lo_f(u64 v) { return __uint_as_float((u32)v); }
__device__ __forceinline__ u32 hi_t(u64 v) { return (u32)(v >> 32); }
__device__ __forceinline__ float sigm(float x) { return 1.0f / (1.0f + expf(-x)); }

// ---- K1: XP = trajectory @ enc_Wi + enc_bh (parallel) + tag-array zeroing ----
#define TT 16
__global__ __launch_bounds__(256, 1)
void k_xp(const float* __restrict__ traj, const float* __restrict__ Wi,
          const float* __restrict__ bh) {
    const int tid = threadIdx.x;
    if (blockIdx.y == 0) {
        // zero all packed-tag arrays (visible to later kernels via stream order)
        const int fid = blockIdx.x * 256 + tid;       // 0..2047
        if (fid < H) {
            g_he[0][fid] = 0ull; g_he[1][fid] = 0ull;
            g_hd[0][fid] = 0ull; g_hd[1][fid] = 0ull;
        }
        u64* xqf = &g_xq[0][0][0];                    // 2*NWG*D = 4096 entries
        xqf[fid] = 0ull; xqf[fid + 2048] = 0ull;
    }
    const int jc = blockIdx.x;     // 0..7 column chunk
    const int t0 = blockIdx.y * TT;
    const int j  = jc * 256 + tid;

    __shared__ float tl[TT * D];
#pragma unroll
    for (int r = 0; r < (TT * D) / 256; ++r)
        tl[r * 256 + tid] = traj[t0 * D + r * 256 + tid];
    __syncthreads();

    float acc[TT];
#pragma unroll
    for (int tt = 0; tt < TT; ++tt) acc[tt] = 0.f;
    for (int i = 0; i < D; ++i) {
        const float wv = Wi[i * Z4 + j];
#pragma unroll
        for (int tt = 0; tt < TT; ++tt) acc[tt] += tl[tt * D + i] * wv;
    }
    const float bv = bh[j];
#pragma unroll
    for (int tt = 0; tt < TT; ++tt)
        g_xp[(t0 + tt) * Z4 + j] = acc[tt] + bv;
}

// ---- K2: encoder recurrence (16 wgs x 512 threads, weights in regs) ----
__global__ __launch_bounds__(NTH, 1)
void k_enc(const float* __restrict__ Wh) {
    const int w   = blockIdx.x;
    const int tid = threadIdx.x;
    const int jl  = tid & 127;       // local z column 0..127
    const int p   = tid >> 7;        // h part 0..3 -> rows [128p,128p+128)
    const int k0  = w * SLICE;
    const int gcol = (jl >> 5) * H + k0 + (jl & 31);   // global z column

    float wh[128];
#pragma unroll
    for (int q = 0; q < 128; ++q)
        wh[q] = Wh[(p * 128 + q) * Z4 + gcol];

    __shared__ float h_lds[H];
    __shared__ float zred[NTH];
    __shared__ float zfin[128];

    float creg = 0.f;   // cell state (tid < SLICE)

    for (int t = 0; t < T; ++t) {
        // issue XP load before the poll so its latency hides under the spin
        float xpv = (p == 0) ? g_xp[t * Z4 + gcol] : 0.f;

        if (t > 0) {
            const u32 want = (u32)t;
            u64 v;
            do { v = aload64(&g_he[t & 1][tid]); } while (hi_t(v) != want);
            h_lds[tid] = lo_f(v);
        } else {
            h_lds[tid] = 0.f;
        }
        __syncthreads();                       // (A)

        float acc = xpv;
#pragma unroll
        for (int q4 = 0; q4 < 32; ++q4) {
            const float4 hv = *reinterpret_cast<const float4*>(&h_lds[p * 128 + q4 * 4]);
            acc += hv.x * wh[q4 * 4 + 0] + hv.y * wh[q4 * 4 + 1] +
                   hv.z * wh[q4 * 4 + 2] + hv.w * wh[q4 * 4 + 3];
        }
        zred[tid] = acc;
        __syncthreads();                       // (B)
        if (tid < 128)
            zfin[tid] = zred[tid] + zred[128 + tid] + zred[256 + tid] + zred[384 + tid];
        __syncthreads();                       // (C)
        if (tid < SLICE) {
            const float zi = zfin[tid], zf = zfin[32 + tid],
                        zg = zfin[64 + tid], zo = zfin[96 + tid];
            const float cn = sigm(zf) * creg + sigm(zi) * tanhf(zg);
            creg = cn;
            const float hn = sigm(zo) * tanhf(cn);
            astore64(&g_he[(t + 1) & 1][k0 + tid], pack2((u32)(t + 1), hn));
        }
        // no trailing barrier needed: next write of h_lds/zred is ordered
        // behind (A)/(B) of the next iteration.
    }
}

// ---- K3: embedding + decoder init (1 wg) ----
__global__ __launch_bounds__(256, 1)
void k_emb(const float* __restrict__ embW, const float* __restrict__ embB,
           const float* __restrict__ diW, const float* __restrict__ diB,
           float* __restrict__ out) {
    const int tid = threadIdx.x;
    __shared__ float h_l[H];
    __shared__ float e_l[EMB];
#pragma unroll
    for (int r = 0; r < H / 256; ++r)
        h_l[r * 256 + tid] = lo_f(g_he[0][r * 256 + tid]);   // tag 512, slot 0
    __syncthreads();

    float acc = embB[tid];
    for (int i = 0; i < H; ++i)
        acc += h_l[i] * embW[i * EMB + tid];
    e_l[tid] = acc;
    out[T * D + tid] = acc;            // embedding output
    __syncthreads();

#pragma unroll
    for (int r = 0; r < H / 256; ++r) {
        const int k = r * 256 + tid;
        float a2 = diB[k];
        for (int e = 0; e < EMB; ++e)
            a2 += e_l[e] * diW[e * H + k];
        g_hd0[k] = a2;
    }
}

// ---- K4: decoder recurrence + per-step output (16 wgs x 512 threads) ----
__global__ __launch_bounds__(NTH, 1)
void k_dec(const float* __restrict__ Wi, const float* __restrict__ Wh,
           const float* __restrict__ bh, const float* __restrict__ Wt,
           const float* __restrict__ bt, float* __restrict__ out) {
    const int w   = blockIdx.x;
    const int tid = threadIdx.x;
    const int jl  = tid & 127;
    const int p   = tid >> 7;        // x rows [32p,32p+32), h rows [128p,128p+128)
    const int k0  = w * SLICE;
    const int gcol = (jl >> 5) * H + k0 + (jl & 31);
    const int d   = tid & 127;       // for x-partial sum
    const int g4  = tid >> 7;        // partial-slot group 0..3

    float wx[32], wh[128];
#pragma unroll
    for (int q = 0; q < 32; ++q)
        wx[q] = Wi[(p * 32 + q) * Z4 + gcol];
#pragma unroll
    for (int q = 0; q < 128; ++q)
        wh[q] = Wh[(p * 128 + q) * Z4 + gcol];
    const float bhz = (tid < 128) ? bh[(tid >> 5) * H + k0 + (tid & 31)] : 0.f;

    __shared__ float h_lds[H];
    __shared__ float xs_lds[D];
    __shared__ float zred[NTH];
    __shared__ float zfin[128];
    __shared__ float hs_lds[SLICE];

    float creg = 0.f;

    for (int s = 0; s < T; ++s) {
        // prefetch this step's output-weight rows (independent of h)
        float wpre[SLICE];
        float btv = 0.f;
        if (tid < D) {
#pragma unroll
            for (int kk = 0; kk < SLICE; ++kk)
                wpre[kk] = Wt[((size_t)s * H + k0 + kk) * D + tid];
            if (w == 0) btv = bt[s * D + tid];
        }

        if (s > 0) {
            const u32 want = (u32)s;
            const int par  = s & 1;
            u64 vh, v0, v1, v2, v3;
            for (;;) {
                vh = aload64(&g_hd[par][tid]);
                v0 = aload64(&g_xq[par][g4 * 4 + 0][d]);
                v1 = aload64(&g_xq[par][g4 * 4 + 1][d]);
                v2 = aload64(&g_xq[par][g4 * 4 + 2][d]);
                v3 = aload64(&g_xq[par][g4 * 4 + 3][d]);
                if ((hi_t(vh) == want) & (hi_t(v0) == want) & (hi_t(v1) == want) &
                    (hi_t(v2) == want) & (hi_t(v3) == want)) break;
            }
            h_lds[tid] = lo_f(vh);
            zred[tid]  = lo_f(v0) + lo_f(v1) + lo_f(v2) + lo_f(v3);
            __syncthreads();
            if (tid < D) {
                const float xv = zred[tid] + zred[128 + tid] + zred[256 + tid] + zred[384 + tid];
                xs_lds[tid] = xv;
                if (w == 0) out[(size_t)(s - 1) * D + tid] = xv;
            }
        } else {
            h_lds[tid] = g_hd0[tid];
            if (tid < D) xs_lds[tid] = 0.f;
        }
        __syncthreads();                       // (A)

        float acc = 0.f;
#pragma unroll
        for (int q4 = 0; q4 < 8; ++q4) {
            const float4 xv = *reinterpret_cast<const float4*>(&xs_lds[p * 32 + q4 * 4]);
            acc += xv.x * wx[q4 * 4 + 0] + xv.y * wx[q4 * 4 + 1] +
                   xv.z * wx[q4 * 4 + 2] + xv.w * wx[q4 * 4 + 3];
        }
#pragma unroll
        for (int q4 = 0; q4 < 32; ++q4) {
            const float4 hv = *reinterpret_cast<const float4*>(&h_lds[p * 128 + q4 * 4]);
            acc += hv.x * wh[q4 * 4 + 0] + hv.y * wh[q4 * 4 + 1] +
                   hv.z * wh[q4 * 4 + 2] + hv.w * wh[q4 * 4 + 3];
        }
        zred[tid] = acc;
        __syncthreads();                       // (B)
        if (tid < 128)
            zfin[tid] = zred[tid] + zred[128 + tid] + zred[256 + tid] + zred[384 + tid] + bhz;
        __syncthreads();                       // (C)
        if (tid < SLICE) {
            const float zi = zfin[tid], zf = zfin[32 + tid],
                        zg = zfin[64 + tid], zo = zfin[96 + tid];
            const float cn = sigm(zf) * creg + sigm(zi) * tanhf(zg);
            creg = cn;
            const float hn = sigm(zo) * tanhf(cn);
            hs_lds[tid] = hn;
            astore64(&g_hd[(s + 1) & 1][k0 + tid], pack2((u32)(s + 1), hn));
        }
        __syncthreads();                       // (D) hs_lds visible
        if (tid < D) {
            float px = btv;
#pragma unroll
            for (int kk = 0; kk < SLICE; ++kk)
                px += hs_lds[kk] * wpre[kk];
            astore64(&g_xq[(s + 1) & 1][w][tid], pack2((u32)(s + 1), px));
        }
    }

    // final reconstruction row: x^{T} (tag T, slot T&1 == 0), summed by wg 0
    if (w == 0) {
        const u32 want = (u32)T;
        u64 v0, v1, v2, v3;
        for (;;) {
            v0 = aload64(&g_xq[0][g4 * 4 + 0][d]);
            v1 = aload64(&g_xq[0][g4 * 4 + 1][d]);
            v2 = aload64(&g_xq[0][g4 * 4 + 2][d]);
            v3 = aload64(&g_xq[0][g4 * 4 + 3][d]);
            if ((hi_t(v0) == want) & (hi_t(v1) == want) &
                (hi_t(v2) == want) & (hi_t(v3) == want)) break;
        }
        zred[tid] = lo_f(v0) + lo_f(v1) + lo_f(v2) + lo_f(v3);
        __syncthreads();
        if (tid < D)
            out[(size_t)(T - 1) * D + tid] =
                zred[tid] + zred[128 + tid] + zred[256 + tid] + zred[384 + tid];
    }
}

extern "C" void kernel_launch(void* const* d_in, const int* in_sizes, int n_in,
                              void* d_out, int out_size, void* d_ws, size_t ws_size,
                              hipStream_t stream) {
    const float* traj  = (const float*)d_in[0];
    const float* encWi = (const float*)d_in[1];
    const float* encWh = (const float*)d_in[2];
    const float* encbh = (const float*)d_in[3];
    const float* embW  = (const float*)d_in[4];
    const float* embB  = (const float*)d_in[5];
    const float* diW   = (const float*)d_in[6];
    const float* diB   = (const float*)d_in[7];
    const float* decWi = (const float*)d_in[8];
    const float* decWh = (const float*)d_in[9];
    const float* decbh = (const float*)d_in[10];
    const float* doW   = (const float*)d_in[11];
    const float* dob   = (const float*)d_in[12];
    float* out = (float*)d_out;

    k_xp<<<dim3(8, T / TT), dim3(256), 0, stream>>>(traj, encWi, encbh);
    k_enc<<<dim3(NWG), dim3(NTH), 0, stream>>>(encWh);
    k_emb<<<dim3(1), dim3(256), 0, stream>>>(embW, embB, diW, diB, out);
    k_dec<<<dim3(NWG), dim3(NTH), 0, stream>>>(decWi, decWh, decbh, doW, dob, out);
}